// Round 11
// baseline (335.385 us; speedup 1.0000x reference)
//
#include <hip/hip_runtime.h>

#define BN_EPS 1e-5f

typedef __attribute__((ext_vector_type(8))) short bf16x8;
typedef __attribute__((ext_vector_type(4))) float f32x4;
typedef __attribute__((ext_vector_type(2))) float f32x2;

__device__ __forceinline__ short f2bf(float f) {
    union { float f; unsigned u; } v; v.f = f;
    unsigned r = (v.u + 0x7fffu + ((v.u >> 16) & 1u)) >> 16;
    return (short)r;
}
__device__ __forceinline__ float bflo(unsigned d) {
    union { unsigned u; float f; } v; v.u = d << 16; return v.f;
}
__device__ __forceinline__ float bfhi(unsigned d) {
    union { unsigned u; float f; } v; v.u = d & 0xffff0000u; return v.f;
}
__device__ __forceinline__ unsigned pk2bf(float lo, float hi) {
    return (unsigned)(unsigned short)f2bf(lo) | ((unsigned)(unsigned short)f2bf(hi) << 16);
}

// ---------------- fp8 e4m3 (OCP) encode/decode -----------------------------
#if __has_builtin(__builtin_amdgcn_cvt_pk_fp8_f32)
__device__ __forceinline__ unsigned char f32_to_fp8(float v) {
    int pk = __builtin_amdgcn_cvt_pk_fp8_f32(v, v, 0, false);
    return (unsigned char)(pk & 0xff);
}
#else
__device__ __forceinline__ unsigned char f32_to_fp8(float v) {
    unsigned u = __float_as_uint(v);
    unsigned s = (u >> 24) & 0x80;
    float af = fabsf(v);
    if (af > 448.f) return (unsigned char)(s | 0x7E);
    if (af < 0.0009765625f) return (unsigned char)s;
    int e = ilogbf(af);
    if (e < -6) {
        int q = __float2int_rn(af * 512.f);
        return (unsigned char)(s | q);
    }
    float sc = ldexpf(af, 3 - e);
    int q = __float2int_rn(sc);
    if (q == 16) { q = 8; ++e; if (e > 8) return (unsigned char)(s | 0x7E); }
    return (unsigned char)(s | ((e + 7) << 3) | (q - 8));
}
#endif

#if __has_builtin(__builtin_amdgcn_cvt_pk_f32_fp8)
__device__ __forceinline__ void fp8x4_acc(unsigned d, float w,
                                          float& a0, float& a1, float& a2, float& a3) {
    f32x2 lo = __builtin_amdgcn_cvt_pk_f32_fp8(d, false);
    f32x2 hi = __builtin_amdgcn_cvt_pk_f32_fp8(d, true);
    a0 = fmaf(w, lo[0], a0); a1 = fmaf(w, lo[1], a1);
    a2 = fmaf(w, hi[0], a2); a3 = fmaf(w, hi[1], a3);
}
#else
__device__ __forceinline__ float fp8dec(unsigned byte) {
    unsigned em = byte & 0x7f;
    float m = __uint_as_float(em << 20) * 1.3292279957849159e36f;  // 2^120
    unsigned r = __float_as_uint(m) | ((byte & 0x80u) << 24);
    return __uint_as_float(r);
}
__device__ __forceinline__ void fp8x4_acc(unsigned d, float w,
                                          float& a0, float& a1, float& a2, float& a3) {
    a0 = fmaf(w, fp8dec(d & 0xff), a0);
    a1 = fmaf(w, fp8dec((d >> 8) & 0xff), a1);
    a2 = fmaf(w, fp8dec((d >> 16) & 0xff), a2);
    a3 = fmaf(w, fp8dec(d >> 24), a3);
}
#endif

// ---------------------------------------------------------------------------
// Fused prologue (single dispatch): CSR offsets + W transposes + zero stats.
// ---------------------------------------------------------------------------
__global__ __launch_bounds__(256) void prologue_k(const int* __restrict__ dst,
                                                  int* __restrict__ off, int E, int N,
                                                  const float* __restrict__ W0, short* __restrict__ Wt0,
                                                  const float* __restrict__ W1, short* __restrict__ Wt1,
                                                  const float* __restrict__ W2, short* __restrict__ Wt2,
                                                  float* __restrict__ stats) {
    int b = blockIdx.x;
    const int nbOff = (E + 256) / 256;
    if (b < nbOff) {
        int i = b * 256 + threadIdx.x;
        if (i > E) return;
        int cur  = (i < E) ? dst[i] : N;
        int prev = (i == 0) ? -1 : dst[i - 1];
        for (int n = prev + 1; n <= cur; ++n) off[n] = i;
        return;
    }
    b -= nbOff;
    if (b < 64) {
        int i = b * 256 + threadIdx.x;
        int c = i / 128, k = i % 128;
        Wt0[i] = f2bf(W0[k * 128 + c]);
        return;
    }
    b -= 64;
    if (b < 64) {
        int i = b * 256 + threadIdx.x;
        int c = i / 128, k = i % 128;
        Wt1[i] = f2bf(W1[k * 128 + c]);
        return;
    }
    b -= 64;
    if (b < 32) {
        int i = b * 256 + threadIdx.x;
        int c = i / 128, k = i % 128;
        Wt2[i] = f2bf(W2[k * 64 + c]);
        return;
    }
    b -= 32;
    if (b == 0) {
        stats[threadIdx.x] = 0.f;
        stats[threadIdx.x + 256] = 0.f;
    }
}

// ---------------------------------------------------------------------------
// MFMA GEMM, A-input fusion modes (BN finalize folded into MODE 1/2).
// ---------------------------------------------------------------------------
template <int OUTC, int MODE, bool OUT8>
__global__ __launch_bounds__(256) void mgemm_k(const void* __restrict__ Xp,
                                               const short* __restrict__ Wt,
                                               void* __restrict__ Mout,
                                               const float* __restrict__ stats,
                                               const float* __restrict__ gamma,
                                               const float* __restrict__ beta,
                                               float invN,
                                               const void* __restrict__ Rp,
                                               short* __restrict__ X1, int N) {
    constexpr int NR = OUTC / 16;
    __shared__ short sW[OUTC][136];
    __shared__ float sSS[256];

    const int tid = threadIdx.x;
    if constexpr (MODE != 0) {
        if (tid < 128) {
            float mu  = stats[tid] * invN;
            float var = fmaf(-mu, mu, stats[128 + tid] * invN);
            float sc  = gamma[tid] * rsqrtf(var + BN_EPS);
            sSS[tid]       = sc;
            sSS[128 + tid] = fmaf(-mu, sc, beta[tid]);
        }
    }
    for (int q = tid; q < OUTC * 16; q += 256) {
        int r = q >> 4, s = q & 15;
        *(int4*)&sW[r][s * 8] = ((const int4*)Wt)[q];
    }
    __syncthreads();

    const int wave = tid >> 6, lane = tid & 63;
    const int lr = lane & 15, lg = lane >> 4;
    const int row0 = blockIdx.x * 128 + wave * 32;

    f32x4 acc[2][NR];
    #pragma unroll
    for (int m = 0; m < 2; ++m)
        #pragma unroll
        for (int n = 0; n < NR; ++n) acc[m][n] = (f32x4){0.f, 0.f, 0.f, 0.f};

    #pragma unroll
    for (int kk = 0; kk < 4; ++kk) {
        bf16x8 a[2];
        const int ch0 = kk * 32 + lg * 8;
        #pragma unroll
        for (int m = 0; m < 2; ++m) {
            int row = row0 + m * 16 + lr;
            float v[8] = {0.f, 0.f, 0.f, 0.f, 0.f, 0.f, 0.f, 0.f};
            if (row < N) {
                if constexpr (MODE == 0) {
                    const float4* p = (const float4*)((const float*)Xp + (size_t)row * 128 + ch0);
                    float4 h0 = p[0], h1 = p[1];
                    v[0] = h0.x; v[1] = h0.y; v[2] = h0.z; v[3] = h0.w;
                    v[4] = h1.x; v[5] = h1.y; v[6] = h1.z; v[7] = h1.w;
                } else {
                    int4 hb = *(const int4*)((const short*)Xp + (size_t)row * 128 + ch0);
                    v[0] = bflo(hb.x); v[1] = bfhi(hb.x);
                    v[2] = bflo(hb.y); v[3] = bfhi(hb.y);
                    v[4] = bflo(hb.z); v[5] = bfhi(hb.z);
                    v[6] = bflo(hb.w); v[7] = bfhi(hb.w);
                    float sc[8], sh[8];
                    #pragma unroll
                    for (int k = 0; k < 8; ++k) {
                        sc[k] = sSS[ch0 + k];
                        sh[k] = sSS[128 + ch0 + k];
                    }
                    float r[8];
                    if constexpr (MODE == 1) {
                        const float4* rp = (const float4*)((const float*)Rp + (size_t)row * 128 + ch0);
                        float4 r0 = rp[0], r1 = rp[1];
                        r[0] = r0.x; r[1] = r0.y; r[2] = r0.z; r[3] = r0.w;
                        r[4] = r1.x; r[5] = r1.y; r[6] = r1.z; r[7] = r1.w;
                    } else {
                        int4 rb = *(const int4*)((const short*)Rp + (size_t)row * 128 + ch0);
                        r[0] = bflo(rb.x); r[1] = bfhi(rb.x);
                        r[2] = bflo(rb.y); r[3] = bfhi(rb.y);
                        r[4] = bflo(rb.z); r[5] = bfhi(rb.z);
                        r[6] = bflo(rb.w); r[7] = bfhi(rb.w);
                    }
                    #pragma unroll
                    for (int k = 0; k < 8; ++k)
                        v[k] = fmaxf(fmaf(v[k], sc[k], sh[k]) + r[k], 0.f);
                }
            }
            #pragma unroll
            for (int k = 0; k < 8; ++k) a[m][k] = f2bf(v[k]);
            if constexpr (MODE == 1) {
                if (row < N) *(bf16x8*)&X1[(size_t)row * 128 + ch0] = a[m];
            }
        }
        #pragma unroll
        for (int n = 0; n < NR; ++n) {
            bf16x8 b = *(const bf16x8*)&sW[n * 16 + lr][kk * 32 + lg * 8];
            acc[0][n] = __builtin_amdgcn_mfma_f32_16x16x32_bf16(a[0], b, acc[0][n], 0, 0, 0);
            acc[1][n] = __builtin_amdgcn_mfma_f32_16x16x32_bf16(a[1], b, acc[1][n], 0, 0, 0);
        }
    }

    #pragma unroll
    for (int m = 0; m < 2; ++m)
        #pragma unroll
        for (int r = 0; r < 4; ++r) {
            int row = row0 + m * 16 + lg * 4 + r;
            if (row < N) {
                if constexpr (OUT8) {
                    #pragma unroll
                    for (int n = 0; n < NR; ++n)
                        ((unsigned char*)Mout)[(size_t)row * OUTC + n * 16 + lr] =
                            f32_to_fp8(acc[m][n][r]);
                } else {
                    #pragma unroll
                    for (int n = 0; n < NR; ++n)
                        ((short*)Mout)[(size_t)row * OUTC + n * 16 + lr] = f2bf(acc[m][n][r]);
                }
            }
        }
}

// ---------------------------------------------------------------------------
// 128-ch fp8 gather, ONE node per wave, 8 EDGES PER WAVE-LOAD.
// Lane = (e3 = lane>>3 edge-slot, q = lane&7 chunk). One dwordx4/lane: a
// wave-load covers 8 full 128B rows (1KB). 2 loads in flight (16 lines).
// 16 fp32 accs/lane (chunk = 16 ch); one 3-stage butterfly per node at end;
// lanes 0..7 store 32B each (256B row, bf16).
// ---------------------------------------------------------------------------
__global__ __launch_bounds__(256) void aggf8_k(const unsigned char* __restrict__ M,
                                               const int* __restrict__ src,
                                               const int* __restrict__ off,
                                               const float* __restrict__ bias,
                                               unsigned* __restrict__ Hb, int N) {
    const int lane = threadIdx.x & 63;
    const int node = blockIdx.x * 4 + (threadIdx.x >> 6);
    if (node >= N) return;
    const int e0 = off[node], e1 = off[node + 1];
    const uint4* __restrict__ Mq = (const uint4*)M;   // 8 uint4 per row
    const int e3 = lane >> 3, q = lane & 7;

    float acc[16];
    #pragma unroll
    for (int k = 0; k < 16; ++k) acc[k] = 0.f;

    for (int base = e0; base < e1; base += 64) {
        const int cnt = min(64, e1 - base);
        int s = (base + lane < e1) ? src[base + lane] : 0;
        for (int j = 0; j < cnt; j += 16) {
            int i0 = j + e3, i1 = j + 8 + e3;
            int c0 = min(i0, cnt - 1);
            int c1 = min(i1, cnt - 1);
            int s0 = __shfl(s, c0), s1 = __shfl(s, c1);
            uint4 d0 = Mq[(size_t)s0 * 8 + q];
            uint4 d1 = Mq[(size_t)s1 * 8 + q];
            float w0 = i0 < cnt ? 1.f : 0.f;
            float w1 = i1 < cnt ? 1.f : 0.f;
            fp8x4_acc(d0.x, w0, acc[0], acc[1], acc[2], acc[3]);
            fp8x4_acc(d0.y, w0, acc[4], acc[5], acc[6], acc[7]);
            fp8x4_acc(d0.z, w0, acc[8], acc[9], acc[10], acc[11]);
            fp8x4_acc(d0.w, w0, acc[12], acc[13], acc[14], acc[15]);
            fp8x4_acc(d1.x, w1, acc[0], acc[1], acc[2], acc[3]);
            fp8x4_acc(d1.y, w1, acc[4], acc[5], acc[6], acc[7]);
            fp8x4_acc(d1.z, w1, acc[8], acc[9], acc[10], acc[11]);
            fp8x4_acc(d1.w, w1, acc[12], acc[13], acc[14], acc[15]);
        }
    }
    // reduce over edge-slot dimension (lane bits 3..5)
    #pragma unroll
    for (int dlt = 8; dlt < 64; dlt <<= 1)
        #pragma unroll
        for (int k = 0; k < 16; ++k) acc[k] += __shfl_xor(acc[k], dlt);

    if (e3 == 0) {                   // lanes 0..7: chunk q -> channels 16q..16q+15
        const float4* bv = (const float4*)&bias[q * 16];
        float4 b0 = bv[0], b1 = bv[1], b2 = bv[2], b3 = bv[3];
        uint4 o0, o1;
        o0.x = pk2bf(acc[0] + b0.x,  acc[1] + b0.y);
        o0.y = pk2bf(acc[2] + b0.z,  acc[3] + b0.w);
        o0.z = pk2bf(acc[4] + b1.x,  acc[5] + b1.y);
        o0.w = pk2bf(acc[6] + b1.z,  acc[7] + b1.w);
        o1.x = pk2bf(acc[8] + b2.x,  acc[9] + b2.y);
        o1.y = pk2bf(acc[10] + b2.z, acc[11] + b2.w);
        o1.z = pk2bf(acc[12] + b3.x, acc[13] + b3.y);
        o1.w = pk2bf(acc[14] + b3.z, acc[15] + b3.w);
        *(uint4*)&Hb[(size_t)node * 64 + q * 8]     = o0;
        *(uint4*)&Hb[(size_t)node * 64 + q * 8 + 4] = o1;
    }
}

// ---------------------------------------------------------------------------
// 64-ch bf16 gather, fp32 out (final layer). Same 8-edges-per-load structure:
// row = 128B, chunk q = 4 dwords = 8 channels, 8 fp32 accs/lane.
// ---------------------------------------------------------------------------
__global__ __launch_bounds__(256) void agg64_k(const short* __restrict__ M,
                                               const int* __restrict__ src,
                                               const int* __restrict__ off,
                                               const float* __restrict__ bias,
                                               float* __restrict__ out, int N) {
    const int lane = threadIdx.x & 63;
    const int node = blockIdx.x * 4 + (threadIdx.x >> 6);
    if (node >= N) return;
    const int e0 = off[node], e1 = off[node + 1];
    const uint4* __restrict__ Mq = (const uint4*)M;   // 8 uint4 per row
    const int e3 = lane >> 3, q = lane & 7;

    float acc[8];
    #pragma unroll
    for (int k = 0; k < 8; ++k) acc[k] = 0.f;

    for (int base = e0; base < e1; base += 64) {
        const int cnt = min(64, e1 - base);
        int s = (base + lane < e1) ? src[base + lane] : 0;
        for (int j = 0; j < cnt; j += 16) {
            int i0 = j + e3, i1 = j + 8 + e3;
            int c0 = min(i0, cnt - 1);
            int c1 = min(i1, cnt - 1);
            int s0 = __shfl(s, c0), s1 = __shfl(s, c1);
            uint4 d0 = Mq[(size_t)s0 * 8 + q];
            uint4 d1 = Mq[(size_t)s1 * 8 + q];
            float w0 = i0 < cnt ? 1.f : 0.f;
            float w1 = i1 < cnt ? 1.f : 0.f;
            acc[0] = fmaf(w0, bflo(d0.x), acc[0]); acc[1] = fmaf(w0, bfhi(d0.x), acc[1]);
            acc[2] = fmaf(w0, bflo(d0.y), acc[2]); acc[3] = fmaf(w0, bfhi(d0.y), acc[3]);
            acc[4] = fmaf(w0, bflo(d0.z), acc[4]); acc[5] = fmaf(w0, bfhi(d0.z), acc[5]);
            acc[6] = fmaf(w0, bflo(d0.w), acc[6]); acc[7] = fmaf(w0, bfhi(d0.w), acc[7]);
            acc[0] = fmaf(w1, bflo(d1.x), acc[0]); acc[1] = fmaf(w1, bfhi(d1.x), acc[1]);
            acc[2] = fmaf(w1, bflo(d1.y), acc[2]); acc[3] = fmaf(w1, bfhi(d1.y), acc[3]);
            acc[4] = fmaf(w1, bflo(d1.z), acc[4]); acc[5] = fmaf(w1, bfhi(d1.z), acc[5]);
            acc[6] = fmaf(w1, bflo(d1.w), acc[6]); acc[7] = fmaf(w1, bfhi(d1.w), acc[7]);
        }
    }
    #pragma unroll
    for (int dlt = 8; dlt < 64; dlt <<= 1)
        #pragma unroll
        for (int k = 0; k < 8; ++k) acc[k] += __shfl_xor(acc[k], dlt);

    if (e3 == 0) {                   // lanes 0..7: channels 8q..8q+7, fp32
        const float4* bv = (const float4*)&bias[q * 8];
        float4 b0 = bv[0], b1 = bv[1];
        *(float4*)&out[(size_t)node * 64 + q * 8] =
            make_float4(acc[0] + b0.x, acc[1] + b0.y, acc[2] + b0.z, acc[3] + b0.w);
        *(float4*)&out[(size_t)node * 64 + q * 8 + 4] =
            make_float4(acc[4] + b1.x, acc[5] + b1.y, acc[6] + b1.z, acc[7] + b1.w);
    }
}

// ---------------------------------------------------------------------------
// BN column stats (sum, sumsq) over bf16 Hb.
// ---------------------------------------------------------------------------
__global__ __launch_bounds__(256) void stats_k(const short* __restrict__ Hb,
                                               float* __restrict__ stats, int N) {
    const int lane = threadIdx.x & 63, wave = threadIdx.x >> 6;
    const unsigned* __restrict__ H32 = (const unsigned*)Hb;
    float2 sum = make_float2(0.f, 0.f), sq = make_float2(0.f, 0.f);
    for (int r = blockIdx.x * 4 + wave; r < N; r += gridDim.x * 4) {
        unsigned d = H32[(size_t)r * 64 + lane];
        float lo = bflo(d), hi = bfhi(d);
        sum.x += lo; sum.y += hi;
        sq.x = fmaf(lo, lo, sq.x); sq.y = fmaf(hi, hi, sq.y);
    }
    __shared__ float sL[4][256];
    sL[wave][lane * 2]           = sum.x;
    sL[wave][lane * 2 + 1]       = sum.y;
    sL[wave][128 + lane * 2]     = sq.x;
    sL[wave][128 + lane * 2 + 1] = sq.y;
    __syncthreads();
    int tid = threadIdx.x;
    float v = sL[0][tid] + sL[1][tid] + sL[2][tid] + sL[3][tid];
    atomicAdd(&stats[tid], v);
}

// ---------------------------------------------------------------------------
extern "C" void kernel_launch(void* const* d_in, const int* in_sizes, int n_in,
                              void* d_out, int out_size, void* d_ws, size_t ws_size,
                              hipStream_t stream) {
    const float* x   = (const float*)d_in[0];
    const int*   src = (const int*)d_in[1];
    const int*   dst = (const int*)d_in[2];
    const float* W0  = (const float*)d_in[3];
    const float* b0  = (const float*)d_in[4];
    const float* W1  = (const float*)d_in[5];
    const float* b1  = (const float*)d_in[6];
    const float* W2  = (const float*)d_in[7];
    const float* b2  = (const float*)d_in[8];
    const float* g0  = (const float*)d_in[9];
    const float* be0 = (const float*)d_in[10];
    const float* g1  = (const float*)d_in[11];
    const float* be1 = (const float*)d_in[12];
    float* out = (float*)d_out;

    const int N = in_sizes[0] / 128;
    const int E = in_sizes[1];

    char*  ws   = (char*)d_ws;
    size_t bufH = (size_t)N * 128 * sizeof(short);
    char*  Mb = ws;                           // N x 128 bytes (fp8 or bf16-64ch)
    short* Hb = (short*)(ws + bufH);          // pre-BN agg output, bf16
    short* X1 = (short*)(ws + 2 * bufH);      // post-layer-1 activations, bf16
    size_t p  = 3 * bufH;
    p = (p + 255) & ~(size_t)255;
    int*   off = (int*)(ws + p);
    p += ((size_t)(N + 1) * sizeof(int) + 255) & ~(size_t)255;
    float* stats0 = (float*)(ws + p); p += 1024;
    float* stats1 = (float*)(ws + p); p += 1024;
    short* Wt0    = (short*)(ws + p); p += 128 * 128 * 2;
    short* Wt1    = (short*)(ws + p); p += 128 * 128 * 2;
    short* Wt2    = (short*)(ws + p); p += 128 * 64 * 2;

    const dim3 blk(256);
    const int nbOff  = (E + 256) / 256;
    const int gPro   = nbOff + 64 + 64 + 32 + 1;
    const int gGemm  = (N + 127) / 128;
    const int gAgg   = (N + 3) / 4;            // one node per wave
    const int gStats = 2048;
    const float invN = 1.f / (float)N;

    prologue_k<<<gPro, blk, 0, stream>>>(dst, off, E, N, W0, Wt0, W1, Wt1, W2, Wt2, stats0);

    // ---- layer 0 ----
    mgemm_k<128, 0, true><<<gGemm, blk, 0, stream>>>(x, Wt0, Mb, nullptr, nullptr, nullptr,
                                                     0.f, nullptr, nullptr, N);
    aggf8_k<<<gAgg, blk, 0, stream>>>((unsigned char*)Mb, src, off, b0, (unsigned*)Hb, N);
    stats_k<<<gStats, blk, 0, stream>>>(Hb, stats0, N);

    // ---- layer 1 ----
    mgemm_k<128, 1, true><<<gGemm, blk, 0, stream>>>(Hb, Wt1, Mb, stats0, g0, be0, invN,
                                                     x, X1, N);
    aggf8_k<<<gAgg, blk, 0, stream>>>((unsigned char*)Mb, src, off, b1, (unsigned*)Hb, N);
    stats_k<<<gStats, blk, 0, stream>>>(Hb, stats1, N);

    // ---- layer 2 ----
    mgemm_k<64, 2, false><<<gGemm, blk, 0, stream>>>(Hb, Wt2, Mb, stats1, g1, be1, invN,
                                                     X1, nullptr, N);
    agg64_k<<<gAgg, blk, 0, stream>>>((short*)Mb, src, off, b2, out, N);
}